// Round 12
// baseline (63.797 us; speedup 1.0000x reference)
//
#include <hip/hip_runtime.h>
#include <hip/hip_bf16.h>
#include <cmath>

namespace {

typedef __attribute__((ext_vector_type(8))) short bf16x8;
typedef __attribute__((ext_vector_type(4))) float f32x4;

constexpr float kNegInf = -1000000000.0f;
constexpr float kSlope  = 0.2f;
constexpr float kLog2e  = 1.44269504088896340736f;

__device__ __forceinline__ unsigned short f2bf(float x) {
  unsigned int u = __float_as_uint(x);
  u = (u + 0x7FFFu + ((u >> 16) & 1u)) >> 16;  // RNE
  return (unsigned short)u;
}
// packed pair via v_cvt_pk_bf16_f32
__device__ __forceinline__ unsigned int f2bf2(float a, float b) {
  __hip_bfloat162 t = __float22bfloat162_rn(float2{a, b});
  union { __hip_bfloat162 h; unsigned int u; } c;
  c.h = t;
  return c.u;
}
__device__ __forceinline__ float exp2_hw(float x) {
#if __has_builtin(__builtin_amdgcn_exp2f)
  return __builtin_amdgcn_exp2f(x);
#else
  float r;
  asm("v_exp_f32 %0, %1\n\ts_nop 1" : "=v"(r) : "v"(x));
  return r;
#endif
}

// ---------------- ws layout ----------------
// [0)      ushort wf[18432]   [W | wa1 wa2] B-frag order, bf16 (wa log2e-scaled)
// [36864)  uint   adjp[512]
// [38912)  float  ba[2]       {log2e*Wb.a1, log2e*Wb.a2}

__global__ void prep(const float* __restrict__ Ww, const float* __restrict__ Wb,
                     const float* __restrict__ a1v, const float* __restrict__ a2v,
                     const int* __restrict__ adj,
                     unsigned short* __restrict__ wf, unsigned int* __restrict__ adjp,
                     float* __restrict__ ba) {
  const int tid = blockIdx.x * 256 + threadIdx.x;  // grid 72*256 = 18432 exactly
  // frag order: wf[g][kc][lane][j] = B[k = kc*32 + (lane>>4)*8 + j][col = g*16 + (lane&15)]
  {
    const int j = tid & 7, l = (tid >> 3) & 63, kc = (tid >> 9) & 3, g = tid >> 11;
    const int k = kc * 32 + ((l >> 4) << 3) + j;
    const int c = l & 15;
    float x = 0.f;
    if (g < 8) {
      x = Ww[k * 128 + g * 16 + c];
    } else if (c < 2) {
      const float* av = (c == 0) ? a1v : a2v;
      float s = 0.f;
      for (int q = 0; q < 32; ++q) {
        f32x4 wv = *(const f32x4*)(Ww + k * 128 + q * 4);
        f32x4 aa = *(const f32x4*)(av + q * 4);
        s = fmaf(wv[0], aa[0], fmaf(wv[1], aa[1], fmaf(wv[2], aa[2], fmaf(wv[3], aa[3], s))));
      }
      x = s * kLog2e;  // wa1/wa2, pre-scaled for exp2 domain
    }
    wf[tid] = f2bf(x);
  }
  if (tid < 512) {
    const int row = tid >> 2, wd = tid & 3;
    const int* ap = adj + row * 128 + wd * 32;
    unsigned int bits = 0u;
#pragma unroll
    for (int b = 0; b < 32; ++b) bits |= (ap[b] != 0 ? (1u << b) : 0u);
    adjp[tid] = bits;
  }
  if (tid >= 18368) {  // last wave: ba via butterfly
    const int l = tid - 18368;
    float p1 = Wb[l] * a1v[l] + Wb[l + 64] * a1v[l + 64];
    float p2 = Wb[l] * a2v[l] + Wb[l + 64] * a2v[l + 64];
#pragma unroll
    for (int m = 1; m < 64; m <<= 1) {
      p1 += __shfl_xor(p1, m);
      p2 += __shfl_xor(p2, m);
    }
    if (l == 0) {
      ba[0] = p1 * kLog2e;
      ba[1] = p2 * kLog2e;
    }
  }
}

// LDS: 33792 B; VGPR bound (512,4) -> 128/wave -> 2 blocks/CU = 16 waves/CU
union SMemU {
  struct {
    unsigned short Whs[8][4][64][8];  // 32768: Wh in B-frag order
    float f1s[128];                   // log2 domain
    float f2s[128];
  } a;
  float stage[8][4][132];             // 16896 — per-wave 4-row store stage (aliases Whs head)
};

__global__ __launch_bounds__(512, 4) void gat_pipe(
    const float* __restrict__ h,     // [BS][128][128]
    const float* __restrict__ Wb,    // [128]
    const float* __restrict__ abp,   // [1]
    const unsigned short* __restrict__ wf,
    const unsigned int* __restrict__ adjp,
    const float* __restrict__ ba,
    float* __restrict__ out,         // [BS][128][128]
    int BS) {
  __shared__ SMemU sm;
  const int t    = threadIdx.x;
  const int lane = t & 63;
  const int w    = t >> 6;      // wave 0..7
  const int lr   = lane & 15;
  const int lg   = lane >> 4;   // 0..3
  const int R0   = w * 16;      // this wave's 16 rows
  const float ab2 = abp[0] * kLog2e;
  const float ba1 = ba[0], ba2v = ba[1];

  float wbc[8];
#pragma unroll
  for (int g = 0; g < 8; ++g) wbc[g] = Wb[g * 16 + lr];

  // adjacency for this lane's P-row: identical for every bs -> hoisted
  unsigned int awq[4];
  {
    const int rq = (R0 + lr) * 4;
#pragma unroll
    for (int kc = 0; kc < 4; ++kc) awq[kc] = adjp[rq + kc];
  }

  constexpr int NB = 2;
  const int bs0 = blockIdx.x * NB;

  // ---- prologue: issue h loads for problem bs0 (row R0+lr) ----
  f32x4 pre[8];
  {
    const float* p = h + (size_t)bs0 * 16384 + (R0 + lr) * 128;
#pragma unroll
    for (int kc = 0; kc < 4; ++kc) {
      pre[kc * 2]     = *(const f32x4*)(p + kc * 32 + lg * 8);
      pre[kc * 2 + 1] = *(const f32x4*)(p + kc * 32 + lg * 8 + 4);
    }
  }

#pragma unroll
  for (int it = 0; it < NB; ++it) {
    const int bs = bs0 + it;
    if (bs >= BS) break;

    // ---- convert pre -> A-frags ----
    bf16x8 ha[4];
#pragma unroll
    for (int kc = 0; kc < 4; ++kc) {
      const f32x4 v0 = pre[kc * 2];
      const f32x4 v1 = pre[kc * 2 + 1];
      union { bf16x8 v; unsigned int u[4]; } pk;
      pk.u[0] = f2bf2(v0[0], v0[1]);
      pk.u[1] = f2bf2(v0[2], v0[3]);
      pk.u[2] = f2bf2(v1[0], v1[1]);
      pk.u[3] = f2bf2(v1[2], v1[3]);
      ha[kc] = pk.v;
    }

    // ---- matmul1: [Wh | f1 f2] = bf16(h) @ wf  (B-frags from global/L2) ----
    f32x4 acc[9];
#pragma unroll
    for (int g = 0; g < 9; ++g) acc[g] = (f32x4){0.f, 0.f, 0.f, 0.f};
#pragma unroll
    for (int g = 0; g < 9; ++g)
#pragma unroll
      for (int kc = 0; kc < 4; ++kc) {
        const bf16x8 bh = *(const bf16x8*)(wf + ((g * 4 + kc) * 64 + lane) * 8);
        acc[g] = __builtin_amdgcn_mfma_f32_16x16x32_bf16(ha[kc], bh, acc[g], 0, 0, 0);
      }

    // ---- prefetch next problem's h (issued AFTER matmul1's wf loads; only
    //      stores are younger in the vmcnt FIFO -> no poisoning) ----
    if (it + 1 < NB && bs + 1 < BS) {
      __builtin_amdgcn_sched_barrier(0);
      const float* p = h + (size_t)(bs + 1) * 16384 + (R0 + lr) * 128;
#pragma unroll
      for (int kc = 0; kc < 4; ++kc) {
        pre[kc * 2]     = *(const f32x4*)(p + kc * 32 + lg * 8);
        pre[kc * 2 + 1] = *(const f32x4*)(p + kc * 32 + lg * 8 + 4);
      }
      __builtin_amdgcn_sched_barrier(0);
    }

    __syncthreads();  // A: all waves done with prev iter's LDS reads (incl. stage alias)

    // ---- bias post-add + f1/f2 scatter + Wh -> LDS (B-frag order) ----
    // C/D layout: row = R0 + lg*4 + r, col = g*16 + lr
#pragma unroll
    for (int r = 0; r < 4; ++r) {
#pragma unroll
      for (int g = 0; g < 8; ++g) acc[g][r] += wbc[g];
      const int row = R0 + lg * 4 + r;
      if (lr == 0)      sm.a.f1s[row] = acc[8][r] + ba1;
      else if (lr == 1) sm.a.f2s[row] = acc[8][r] + ba2v;
    }
#pragma unroll
    for (int g = 0; g < 8; ++g) {
      const unsigned int plo = f2bf2(acc[g][0], acc[g][1]);
      const unsigned int phi = f2bf2(acc[g][2], acc[g][3]);
      const int lp = (2 * (w & 1) + (lg >> 1)) * 16 + lr;
      const int jb = (lg & 1) * 4;
      *(uint2*)(&sm.a.Whs[g][w >> 1][lp][jb]) = make_uint2(plo, phi);
    }
    __syncthreads();  // B: Whs/f1/f2 visible to all waves

    // ---- P-build: single pass, log2 domain ----
    bf16x8 af[4];
    float s0 = 0.f;
    const float f1i = sm.a.f1s[R0 + lr] + ab2;
#pragma unroll
    for (int kc = 0; kc < 4; ++kc) {
      const f32x4 fv0 = *(const f32x4*)(&sm.a.f2s[kc * 32 + lg * 8]);
      const f32x4 fv1 = *(const f32x4*)(&sm.a.f2s[kc * 32 + lg * 8 + 4]);
      const unsigned int aw = awq[kc];
      union { bf16x8 v; unsigned int u[4]; } pk;
#pragma unroll
      for (int qq = 0; qq < 4; ++qq) {
        float e[2];
#pragma unroll
        for (int hh = 0; hh < 2; ++hh) {
          const int q = qq * 2 + hh;
          const float fj = (q < 4) ? fv0[q] : fv1[q - 4];
          float x = f1i + fj;
          x = x >= 0.f ? x : kSlope * x;
          x = ((aw >> (lg * 8 + q)) & 1u) ? x : kNegInf;
          e[hh] = exp2_hw(x);  // all-masked row -> 1 each -> uniform (matches jax)
        }
        const unsigned int uu = f2bf2(e[0], e[1]);
        pk.u[qq] = uu;
        s0 += __uint_as_float(uu << 16) + __uint_as_float(uu & 0xffff0000u);
      }
      af[kc] = pk.v;
    }
    s0 += __shfl_xor(s0, 16);
    s0 += __shfl_xor(s0, 32);  // full row sum of bf16-rounded P

    // ---- matmul2: h'·l = P @ Wh ----
    f32x4 acc2[8];
#pragma unroll
    for (int g = 0; g < 8; ++g) acc2[g] = (f32x4){0.f, 0.f, 0.f, 0.f};
#pragma unroll
    for (int g = 0; g < 8; ++g)
#pragma unroll
      for (int kc = 0; kc < 4; ++kc) {
        const bf16x8 bw = *(const bf16x8*)(&sm.a.Whs[g][kc][lane][0]);
        acc2[g] = __builtin_amdgcn_mfma_f32_16x16x32_bf16(af[kc], bw, acc2[g], 0, 0, 0);
      }
    __syncthreads();  // C: all Whs/f2s reads done before stage (alias) is written

    // ---- normalize + elu + divergence-free 4-pass staged store ----
    float inv[4];
#pragma unroll
    for (int r = 0; r < 4; ++r) {
      const float lsum = __shfl(s0, (lane & 48) | (lg * 4 + r));
      inv[r] = __builtin_amdgcn_rcpf(lsum);
    }
    float* oblk = out + (size_t)bs * 16384;
#pragma unroll
    for (int p = 0; p < 4; ++p) {
      // every lane writes row (lg*4 + p): its 8 g-columns
#pragma unroll
      for (int g = 0; g < 8; ++g) {
        float v = acc2[g][p] * inv[p];
        v = v > 0.f ? v : __expf(v) - 1.0f;
        sm.stage[w][lg][g * 16 + lr] = v;
      }
      // every lane reads one 32-B slice of row (lane>>4) and stores coalesced
      // (wave-local RAW/WAR on stage: DS ops in-order within the wave)
      const int col0 = (lane & 15) * 8;
      const f32x4 v0 = *(const f32x4*)(&sm.stage[w][lane >> 4][col0]);
      const f32x4 v1 = *(const f32x4*)(&sm.stage[w][lane >> 4][col0 + 4]);
      float* orow = oblk + (size_t)(R0 + (lane >> 4) * 4 + p) * 128 + col0;
      *(f32x4*)orow       = v0;
      *(f32x4*)(orow + 4) = v1;
    }
  }
}

}  // namespace

extern "C" void kernel_launch(void* const* d_in, const int* in_sizes, int n_in,
                              void* d_out, int out_size, void* d_ws, size_t ws_size,
                              hipStream_t stream) {
  const float* h   = (const float*)d_in[0];
  const float* Ww  = (const float*)d_in[1];
  const float* Wb  = (const float*)d_in[2];
  const float* a1v = (const float*)d_in[3];
  const float* a2v = (const float*)d_in[4];
  const float* ab  = (const float*)d_in[5];
  const int*   adj = (const int*)d_in[6];
  float* out = (float*)d_out;

  unsigned short* wf   = (unsigned short*)d_ws;
  unsigned int*   adjp = (unsigned int*)((char*)d_ws + 36864);
  float*          ba   = (float*)((char*)d_ws + 38912);

  hipLaunchKernelGGL(prep, dim3(72), dim3(256), 0, stream, Ww, Wb, a1v, a2v, adj, wf, adjp, ba);

  const int BS = in_sizes[0] / 16384;  // 1024
  const int grid = (BS + 1) / 2;
  hipLaunchKernelGGL(gat_pipe, dim3(grid), dim3(512), 0, stream,
                     h, Wb, ab, wf, adjp, ba, out, BS);
}

// Round 13
// 43.743 us; speedup vs baseline: 1.4585x; 1.4585x over previous
//
#include <hip/hip_runtime.h>
#include <hip/hip_bf16.h>
#include <cmath>

namespace {

typedef __attribute__((ext_vector_type(8))) short bf16x8;
typedef __attribute__((ext_vector_type(4))) float f32x4;

constexpr float kNegInf = -1000000000.0f;
constexpr float kSlope  = 0.2f;
constexpr float kLog2e  = 1.44269504088896340736f;

__device__ __forceinline__ unsigned short f2bf(float x) {
  unsigned int u = __float_as_uint(x);
  u = (u + 0x7FFFu + ((u >> 16) & 1u)) >> 16;  // RNE
  return (unsigned short)u;
}
// packed pair via v_cvt_pk_bf16_f32
__device__ __forceinline__ unsigned int f2bf2(float a, float b) {
  __hip_bfloat162 t = __float22bfloat162_rn(float2{a, b});
  union { __hip_bfloat162 h; unsigned int u; } c;
  c.h = t;
  return c.u;
}
__device__ __forceinline__ float exp2_hw(float x) {
#if __has_builtin(__builtin_amdgcn_exp2f)
  return __builtin_amdgcn_exp2f(x);
#else
  float r;
  asm("v_exp_f32 %0, %1\n\ts_nop 1" : "=v"(r) : "v"(x));
  return r;
#endif
}

// ---------------- ws layout ----------------
// [0)      ushort wf[18432]   [W | wa1 wa2] B-frag order, bf16 (wa log2e-scaled)
// [36864)  uint   adjp[512]
// [38912)  float  ba[2]       {log2e*Wb.a1, log2e*Wb.a2}

__global__ void prep(const float* __restrict__ Ww, const float* __restrict__ Wb,
                     const float* __restrict__ a1v, const float* __restrict__ a2v,
                     const int* __restrict__ adj,
                     unsigned short* __restrict__ wf, unsigned int* __restrict__ adjp,
                     float* __restrict__ ba) {
  const int tid = blockIdx.x * 256 + threadIdx.x;  // grid 72*256 = 18432 exactly
  // frag order: wf[g][kc][lane][j] = B[k = kc*32 + (lane>>4)*8 + j][col = g*16 + (lane&15)]
  {
    const int j = tid & 7, l = (tid >> 3) & 63, kc = (tid >> 9) & 3, g = tid >> 11;
    const int k = kc * 32 + ((l >> 4) << 3) + j;
    const int c = l & 15;
    float x = 0.f;
    if (g < 8) {
      x = Ww[k * 128 + g * 16 + c];
    } else if (c < 2) {
      const float* av = (c == 0) ? a1v : a2v;
      float s = 0.f;
      for (int q = 0; q < 32; ++q) {
        f32x4 wv = *(const f32x4*)(Ww + k * 128 + q * 4);
        f32x4 aa = *(const f32x4*)(av + q * 4);
        s = fmaf(wv[0], aa[0], fmaf(wv[1], aa[1], fmaf(wv[2], aa[2], fmaf(wv[3], aa[3], s))));
      }
      x = s * kLog2e;  // wa1/wa2, pre-scaled for exp2 domain
    }
    wf[tid] = f2bf(x);
  }
  if (tid < 512) {
    const int row = tid >> 2, wd = tid & 3;
    const int* ap = adj + row * 128 + wd * 32;
    unsigned int bits = 0u;
#pragma unroll
    for (int b = 0; b < 32; ++b) bits |= (ap[b] != 0 ? (1u << b) : 0u);
    adjp[tid] = bits;
  }
  if (tid >= 18368) {  // last wave: ba via butterfly
    const int l = tid - 18368;
    float p1 = Wb[l] * a1v[l] + Wb[l + 64] * a1v[l + 64];
    float p2 = Wb[l] * a2v[l] + Wb[l + 64] * a2v[l + 64];
#pragma unroll
    for (int m = 1; m < 64; m <<= 1) {
      p1 += __shfl_xor(p1, m);
      p2 += __shfl_xor(p2, m);
    }
    if (l == 0) {
      ba[0] = p1 * kLog2e;
      ba[1] = p2 * kLog2e;
    }
  }
}

// LDS: 33792 B -> 4 blocks/CU (16 waves/CU, the measured optimum)
union SMemU {
  struct {
    unsigned short Whs[8][4][64][8];  // 32768: Wh in B-frag order
    float f1s[128];                   // log2 domain
    float f2s[128];
  } a;
  float stage[4][16][132];            // 33792 — aliases Whs+f1s+f2s (dead by epilogue)
};

__global__ __launch_bounds__(256, 4) void gat_mfma(
    const float* __restrict__ h,     // [BS][128][128]
    const float* __restrict__ Wb,    // [128]
    const float* __restrict__ abp,   // [1]
    const unsigned short* __restrict__ wf,
    const unsigned int* __restrict__ adjp,
    const float* __restrict__ ba,
    float* __restrict__ out) {       // [BS][128][128]
  __shared__ SMemU sm;
  const int t    = threadIdx.x;
  const int lane = t & 63;
  const int w    = t >> 6;       // wave 0..3
  const int lr   = lane & 15;
  const int lg   = lane >> 4;    // 0..3
  const int bs   = blockIdx.x;
  const int R0   = w * 32;
  const float ab2 = abp[0] * kLog2e;
  const float ba1 = ba[0], ba2v = ba[1];

  // adjacency rows for this thread's two P-rows: loop-invariant, L2-broadcast
  unsigned int aw0q[4], aw1q[4];
  {
    const int rq0 = (R0 + lr) * 4, rq1 = (R0 + 16 + lr) * 4;
#pragma unroll
    for (int kc = 0; kc < 4; ++kc) {
      aw0q[kc] = adjp[rq0 + kc];
      aw1q[kc] = adjp[rq1 + kc];
    }
  }

  // ---------------- matmul1: [Wh | f1 f2] = bf16(h) @ bf16([W | wa1 wa2]) ----------------
  const float* hblk = h + (size_t)bs * 16384;

  bf16x8 ha[2][4];
#pragma unroll
  for (int rt = 0; rt < 2; ++rt)
#pragma unroll
    for (int kc = 0; kc < 4; ++kc) {
      const float* p = hblk + (R0 + rt * 16 + lr) * 128 + kc * 32 + lg * 8;
      f32x4 v0 = *(const f32x4*)p;
      f32x4 v1 = *(const f32x4*)(p + 4);
      union { bf16x8 v; unsigned int u[4]; } pk;
      pk.u[0] = f2bf2(v0[0], v0[1]);
      pk.u[1] = f2bf2(v0[2], v0[3]);
      pk.u[2] = f2bf2(v1[0], v1[1]);
      pk.u[3] = f2bf2(v1[2], v1[3]);
      ha[rt][kc] = pk.v;
    }

  f32x4 acc[2][9];
#pragma unroll
  for (int rt = 0; rt < 2; ++rt)
#pragma unroll
    for (int g = 0; g < 9; ++g) acc[rt][g] = (f32x4){0.f, 0.f, 0.f, 0.f};

#pragma unroll
  for (int g = 0; g < 9; ++g)
#pragma unroll
    for (int kc = 0; kc < 4; ++kc) {
      const bf16x8 bh = *(const bf16x8*)(wf + ((g * 4 + kc) * 64 + lane) * 8);
      acc[0][g] = __builtin_amdgcn_mfma_f32_16x16x32_bf16(ha[0][kc], bh, acc[0][g], 0, 0, 0);
      acc[1][g] = __builtin_amdgcn_mfma_f32_16x16x32_bf16(ha[1][kc], bh, acc[1][g], 0, 0, 0);
    }

  // ---- bias + f1/f2 scatter + Wh -> LDS (B-frag order, bf16) ----
  float wbc[8];
#pragma unroll
  for (int g = 0; g < 8; ++g) wbc[g] = Wb[g * 16 + lr];

#pragma unroll
  for (int rt = 0; rt < 2; ++rt) {
#pragma unroll
    for (int r = 0; r < 4; ++r) {
      // C/D layout: row = R0 + rt*16 + lg*4 + r, col = g*16 + lr
#pragma unroll
      for (int g = 0; g < 8; ++g) acc[rt][g][r] += wbc[g];
      const int row = R0 + rt * 16 + lg * 4 + r;
      if (lr == 0)      sm.a.f1s[row] = acc[rt][8][r] + ba1;
      else if (lr == 1) sm.a.f2s[row] = acc[rt][8][r] + ba2v;
    }
#pragma unroll
    for (int g = 0; g < 8; ++g) {
      const unsigned int plo = f2bf2(acc[rt][g][0], acc[rt][g][1]);
      const unsigned int phi = f2bf2(acc[rt][g][2], acc[rt][g][3]);
      const int lp = (2 * rt + (lg >> 1)) * 16 + lr;
      const int jb = (lg & 1) * 4;
      *(uint2*)(&sm.a.Whs[g][w][lp][jb]) = make_uint2(plo, phi);
    }
  }
  __syncthreads();

  // ---------------- P-build: single pass, no max-sub (log2 domain, exp2) ----------------
  bf16x8 af[2][4];
  float s0 = 0.f, s1 = 0.f;
  const float f1i0 = sm.a.f1s[R0 + lr] + ab2;
  const float f1i1 = sm.a.f1s[R0 + 16 + lr] + ab2;
#pragma unroll
  for (int kc = 0; kc < 4; ++kc) {
    const f32x4 fv0 = *(const f32x4*)(&sm.a.f2s[kc * 32 + lg * 8]);
    const f32x4 fv1 = *(const f32x4*)(&sm.a.f2s[kc * 32 + lg * 8 + 4]);
    const unsigned int aw0 = aw0q[kc];
    const unsigned int aw1 = aw1q[kc];
    union { bf16x8 v; unsigned int u[4]; } pk0, pk1;
#pragma unroll
    for (int qq = 0; qq < 4; ++qq) {
      float e0[2], e1[2];
#pragma unroll
      for (int hh = 0; hh < 2; ++hh) {
        const int q = qq * 2 + hh;
        const float fj = (q < 4) ? fv0[q] : fv1[q - 4];
        const unsigned int bit = 1u << (lg * 8 + q);
        float x0 = f1i0 + fj;
        x0 = x0 >= 0.f ? x0 : kSlope * x0;
        x0 = (aw0 & bit) ? x0 : kNegInf;
        e0[hh] = exp2_hw(x0);
        float x1 = f1i1 + fj;
        x1 = x1 >= 0.f ? x1 : kSlope * x1;
        x1 = (aw1 & bit) ? x1 : kNegInf;
        e1[hh] = exp2_hw(x1);
      }
      const unsigned int u0 = f2bf2(e0[0], e0[1]);
      const unsigned int u1 = f2bf2(e1[0], e1[1]);
      pk0.u[qq] = u0;
      pk1.u[qq] = u1;
      s0 += __uint_as_float(u0 << 16) + __uint_as_float(u0 & 0xffff0000u);
      s1 += __uint_as_float(u1 << 16) + __uint_as_float(u1 & 0xffff0000u);
    }
    af[0][kc] = pk0.v;
    af[1][kc] = pk1.v;
  }
  s0 += __shfl_xor(s0, 16);
  s0 += __shfl_xor(s0, 32);
  s1 += __shfl_xor(s1, 16);
  s1 += __shfl_xor(s1, 32);
  float rs[2] = {s0, s1};

  // ---------------- matmul2: h'·l = P @ Wh ----------------
  f32x4 acc2[2][8];
#pragma unroll
  for (int rt = 0; rt < 2; ++rt)
#pragma unroll
    for (int g = 0; g < 8; ++g) acc2[rt][g] = (f32x4){0.f, 0.f, 0.f, 0.f};

#pragma unroll
  for (int g = 0; g < 8; ++g)
#pragma unroll
    for (int kc = 0; kc < 4; ++kc) {
      const bf16x8 bw = *(const bf16x8*)(&sm.a.Whs[g][kc][lane][0]);
      acc2[0][g] = __builtin_amdgcn_mfma_f32_16x16x32_bf16(af[0][kc], bw, acc2[0][g], 0, 0, 0);
      acc2[1][g] = __builtin_amdgcn_mfma_f32_16x16x32_bf16(af[1][kc], bw, acc2[1][g], 0, 0, 0);
    }
  __syncthreads();  // all Whs reads done before stage overwrites

  // ---------------- normalize + elu + LDS-staged coalesced store ----------------
  float* oblk = out + (size_t)bs * 16384;
#pragma unroll
  for (int rt = 0; rt < 2; ++rt) {
    float inv[4];
#pragma unroll
    for (int r = 0; r < 4; ++r) {
      const float lsum = __shfl(rs[rt], (lane & 48) | (lg * 4 + r));
      inv[r] = __builtin_amdgcn_rcpf(lsum);
    }
#pragma unroll
    for (int r = 0; r < 4; ++r)
#pragma unroll
      for (int g = 0; g < 8; ++g) {
        float v = acc2[rt][g][r] * inv[r];
        v = v > 0.f ? v : __expf(v) - 1.0f;
        sm.stage[w][lg * 4 + r][g * 16 + lr] = v;  // 2-way bank aliasing = free
      }
    // wave-local RAW on stage: compiler inserts lgkmcnt
#pragma unroll
    for (int sstep = 0; sstep < 8; ++sstep) {
      const int row16 = ((sstep & 1) << 3) + (lane >> 3);
      const int cd    = ((sstep >> 1) << 5) + ((lane & 7) << 2);
      f32x4 vv = *(const f32x4*)(&sm.stage[w][row16][cd]);
      *(f32x4*)(oblk + (size_t)(R0 + rt * 16 + row16) * 128 + cd) = vv;
    }
  }
}

}  // namespace

extern "C" void kernel_launch(void* const* d_in, const int* in_sizes, int n_in,
                              void* d_out, int out_size, void* d_ws, size_t ws_size,
                              hipStream_t stream) {
  const float* h   = (const float*)d_in[0];
  const float* Ww  = (const float*)d_in[1];
  const float* Wb  = (const float*)d_in[2];
  const float* a1v = (const float*)d_in[3];
  const float* a2v = (const float*)d_in[4];
  const float* ab  = (const float*)d_in[5];
  const int*   adj = (const int*)d_in[6];
  float* out = (float*)d_out;

  unsigned short* wf   = (unsigned short*)d_ws;
  unsigned int*   adjp = (unsigned int*)((char*)d_ws + 36864);
  float*          ba   = (float*)((char*)d_ws + 38912);

  hipLaunchKernelGGL(prep, dim3(72), dim3(256), 0, stream, Ww, Wb, a1v, a2v, adj, wf, adjp, ba);

  const int BS = in_sizes[0] / 16384;  // 1024
  hipLaunchKernelGGL(gat_mfma, dim3(BS), dim3(256), 0, stream,
                     h, Wb, ab, wf, adjp, ba, out);
}

// Round 14
// 42.859 us; speedup vs baseline: 1.4885x; 1.0206x over previous
//
#include <hip/hip_runtime.h>
#include <hip/hip_bf16.h>
#include <cmath>

namespace {

typedef __attribute__((ext_vector_type(8))) short bf16x8;
typedef __attribute__((ext_vector_type(4))) float f32x4;

constexpr float kNegInf = -1000000000.0f;
constexpr float kSlope  = 0.2f;
constexpr float kLog2e  = 1.44269504088896340736f;

__device__ __forceinline__ unsigned short f2bf(float x) {
  unsigned int u = __float_as_uint(x);
  u = (u + 0x7FFFu + ((u >> 16) & 1u)) >> 16;  // RNE
  return (unsigned short)u;
}
// packed pair via v_cvt_pk_bf16_f32
__device__ __forceinline__ unsigned int f2bf2(float a, float b) {
  __hip_bfloat162 t = __float22bfloat162_rn(float2{a, b});
  union { __hip_bfloat162 h; unsigned int u; } c;
  c.h = t;
  return c.u;
}
__device__ __forceinline__ float exp2_hw(float x) {
#if __has_builtin(__builtin_amdgcn_exp2f)
  return __builtin_amdgcn_exp2f(x);
#else
  float r;
  asm("v_exp_f32 %0, %1\n\ts_nop 1" : "=v"(r) : "v"(x));
  return r;
#endif
}

// ---------------- ws layout ----------------
// [0)      ushort wf[18432]   [W | wa1 wa2] B-frag order, bf16 (wa log2e-scaled)
// [36864)  uint   adjp[512]
// [38912)  float  ba[2]       {log2e*Wb.a1, log2e*Wb.a2}

__global__ void prep(const float* __restrict__ Ww, const float* __restrict__ Wb,
                     const float* __restrict__ a1v, const float* __restrict__ a2v,
                     const int* __restrict__ adj,
                     unsigned short* __restrict__ wf, unsigned int* __restrict__ adjp,
                     float* __restrict__ ba) {
  const int tid = blockIdx.x * 256 + threadIdx.x;  // grid 72*256 = 18432 exactly
  // frag order: wf[g][kc][lane][j] = B[k = kc*32 + (lane>>4)*8 + j][col = g*16 + (lane&15)]
  {
    const int j = tid & 7, l = (tid >> 3) & 63, kc = (tid >> 9) & 3, g = tid >> 11;
    const int k = kc * 32 + ((l >> 4) << 3) + j;
    const int c = l & 15;
    float x = 0.f;
    if (g < 8) {
      x = Ww[k * 128 + g * 16 + c];
    } else if (c < 2) {
      const float* av = (c == 0) ? a1v : a2v;
      float s = 0.f;
      for (int q = 0; q < 32; ++q) {
        f32x4 wv = *(const f32x4*)(Ww + k * 128 + q * 4);
        f32x4 aa = *(const f32x4*)(av + q * 4);
        s = fmaf(wv[0], aa[0], fmaf(wv[1], aa[1], fmaf(wv[2], aa[2], fmaf(wv[3], aa[3], s))));
      }
      x = s * kLog2e;  // wa1/wa2, pre-scaled for exp2 domain
    }
    wf[tid] = f2bf(x);
  }
  if (tid < 512) {
    const int row = tid >> 2, wd = tid & 3;
    const int* ap = adj + row * 128 + wd * 32;
    unsigned int bits = 0u;
#pragma unroll
    for (int b = 0; b < 32; ++b) bits |= (ap[b] != 0 ? (1u << b) : 0u);
    adjp[tid] = bits;
  }
  if (tid >= 18368) {  // last wave: ba via butterfly
    const int l = tid - 18368;
    float p1 = Wb[l] * a1v[l] + Wb[l + 64] * a1v[l + 64];
    float p2 = Wb[l] * a2v[l] + Wb[l + 64] * a2v[l + 64];
#pragma unroll
    for (int m = 1; m < 64; m <<= 1) {
      p1 += __shfl_xor(p1, m);
      p2 += __shfl_xor(p2, m);
    }
    if (l == 0) {
      ba[0] = p1 * kLog2e;
      ba[1] = p2 * kLog2e;
    }
  }
}

// LDS: 36864 B (one union, three phased lifetimes) -> 4 blocks/CU = 16 waves/CU
union SMemU {
  unsigned short wfs[9][4][64][8];    // 36864: [W|wa] B-frags, live through mm1 only
  struct {
    unsigned short Whs[8][4][64][8];  // 32768: Wh in B-frag order (post-mm1 .. mm2)
    float f1s[128];                   // log2 domain
    float f2s[128];
  } a;
  float stage[4][16][132];            // 33792: epilogue store stage
};

__global__ __launch_bounds__(256, 4) void gat_mfma(
    const float* __restrict__ h,     // [BS][128][128]
    const float* __restrict__ Wb,    // [128]
    const float* __restrict__ abp,   // [1]
    const unsigned short* __restrict__ wf,
    const unsigned int* __restrict__ adjp,
    const float* __restrict__ ba,
    float* __restrict__ out) {       // [BS][128][128]
  __shared__ SMemU sm;
  const int t    = threadIdx.x;
  const int lane = t & 63;
  const int w    = t >> 6;       // wave 0..3
  const int lr   = lane & 15;
  const int lg   = lane >> 4;    // 0..3
  const int bs   = blockIdx.x;
  const int R0   = w * 32;
  const float ab2 = abp[0] * kLog2e;
  const float ba1 = ba[0], ba2v = ba[1];

  // adjacency rows for this thread's two P-rows: loop-invariant, L2-broadcast
  unsigned int aw0q[4], aw1q[4];
  {
    const int rq0 = (R0 + lr) * 4, rq1 = (R0 + 16 + lr) * 4;
#pragma unroll
    for (int kc = 0; kc < 4; ++kc) {
      aw0q[kc] = adjp[rq0 + kc];
      aw1q[kc] = adjp[rq1 + kc];
    }
  }

  // ---- head: coalesced wf loads (L2) + h loads; stage wf -> LDS ----
  f32x4 wtmp[9];
  {
    const f32x4* wfg = (const f32x4*)wf;  // 2304 f32x4 total
#pragma unroll
    for (int p = 0; p < 9; ++p) wtmp[p] = wfg[p * 256 + t];
  }

  const float* hblk = h + (size_t)bs * 16384;
  bf16x8 ha[2][4];
#pragma unroll
  for (int rt = 0; rt < 2; ++rt)
#pragma unroll
    for (int kc = 0; kc < 4; ++kc) {
      const float* p = hblk + (R0 + rt * 16 + lr) * 128 + kc * 32 + lg * 8;
      f32x4 v0 = *(const f32x4*)p;
      f32x4 v1 = *(const f32x4*)(p + 4);
      union { bf16x8 v; unsigned int u[4]; } pk;
      pk.u[0] = f2bf2(v0[0], v0[1]);
      pk.u[1] = f2bf2(v0[2], v0[3]);
      pk.u[2] = f2bf2(v1[0], v1[1]);
      pk.u[3] = f2bf2(v1[2], v1[3]);
      ha[rt][kc] = pk.v;
    }

  {  // stage wf into LDS (linear copy; frag order preserved)
    f32x4* wfl = (f32x4*)sm.wfs;
#pragma unroll
    for (int p = 0; p < 9; ++p) wfl[p * 256 + t] = wtmp[p];
  }
  __syncthreads();  // 0: wfs visible

  // ---------------- matmul1: [Wh | f1 f2] = bf16(h) @ wfs  (B-frags from LDS) ----------------
  f32x4 acc[2][9];
#pragma unroll
  for (int rt = 0; rt < 2; ++rt)
#pragma unroll
    for (int g = 0; g < 9; ++g) acc[rt][g] = (f32x4){0.f, 0.f, 0.f, 0.f};

#pragma unroll
  for (int g = 0; g < 9; ++g)
#pragma unroll
    for (int kc = 0; kc < 4; ++kc) {
      const bf16x8 bh = *(const bf16x8*)(&sm.wfs[g][kc][lane][0]);
      acc[0][g] = __builtin_amdgcn_mfma_f32_16x16x32_bf16(ha[0][kc], bh, acc[0][g], 0, 0, 0);
      acc[1][g] = __builtin_amdgcn_mfma_f32_16x16x32_bf16(ha[1][kc], bh, acc[1][g], 0, 0, 0);
    }
  __syncthreads();  // A: all waves done reading wfs before Whs overwrites it

  // ---- bias + f1/f2 scatter + Wh -> LDS (B-frag order, bf16) ----
  float wbc[8];
#pragma unroll
  for (int g = 0; g < 8; ++g) wbc[g] = Wb[g * 16 + lr];

#pragma unroll
  for (int rt = 0; rt < 2; ++rt) {
#pragma unroll
    for (int r = 0; r < 4; ++r) {
      // C/D layout: row = R0 + rt*16 + lg*4 + r, col = g*16 + lr
#pragma unroll
      for (int g = 0; g < 8; ++g) acc[rt][g][r] += wbc[g];
      const int row = R0 + rt * 16 + lg * 4 + r;
      if (lr == 0)      sm.a.f1s[row] = acc[rt][8][r] + ba1;
      else if (lr == 1) sm.a.f2s[row] = acc[rt][8][r] + ba2v;
    }
#pragma unroll
    for (int g = 0; g < 8; ++g) {
      const unsigned int plo = f2bf2(acc[rt][g][0], acc[rt][g][1]);
      const unsigned int phi = f2bf2(acc[rt][g][2], acc[rt][g][3]);
      const int lp = (2 * rt + (lg >> 1)) * 16 + lr;
      const int jb = (lg & 1) * 4;
      *(uint2*)(&sm.a.Whs[g][w][lp][jb]) = make_uint2(plo, phi);
    }
  }
  __syncthreads();  // B: Whs/f1/f2 visible

  // ---------------- P-build: single pass, no max-sub (log2 domain, exp2) ----------------
  bf16x8 af[2][4];
  float s0 = 0.f, s1 = 0.f;
  const float f1i0 = sm.a.f1s[R0 + lr] + ab2;
  const float f1i1 = sm.a.f1s[R0 + 16 + lr] + ab2;
#pragma unroll
  for (int kc = 0; kc < 4; ++kc) {
    const f32x4 fv0 = *(const f32x4*)(&sm.a.f2s[kc * 32 + lg * 8]);
    const f32x4 fv1 = *(const f32x4*)(&sm.a.f2s[kc * 32 + lg * 8 + 4]);
    const unsigned int aw0 = aw0q[kc];
    const unsigned int aw1 = aw1q[kc];
    union { bf16x8 v; unsigned int u[4]; } pk0, pk1;
#pragma unroll
    for (int qq = 0; qq < 4; ++qq) {
      float e0[2], e1[2];
#pragma unroll
      for (int hh = 0; hh < 2; ++hh) {
        const int q = qq * 2 + hh;
        const float fj = (q < 4) ? fv0[q] : fv1[q - 4];
        const unsigned int bit = 1u << (lg * 8 + q);
        float x0 = f1i0 + fj;
        x0 = x0 >= 0.f ? x0 : kSlope * x0;
        x0 = (aw0 & bit) ? x0 : kNegInf;
        e0[hh] = exp2_hw(x0);
        float x1 = f1i1 + fj;
        x1 = x1 >= 0.f ? x1 : kSlope * x1;
        x1 = (aw1 & bit) ? x1 : kNegInf;
        e1[hh] = exp2_hw(x1);
      }
      const unsigned int u0 = f2bf2(e0[0], e0[1]);
      const unsigned int u1 = f2bf2(e1[0], e1[1]);
      pk0.u[qq] = u0;
      pk1.u[qq] = u1;
      s0 += __uint_as_float(u0 << 16) + __uint_as_float(u0 & 0xffff0000u);
      s1 += __uint_as_float(u1 << 16) + __uint_as_float(u1 & 0xffff0000u);
    }
    af[0][kc] = pk0.v;
    af[1][kc] = pk1.v;
  }
  s0 += __shfl_xor(s0, 16);
  s0 += __shfl_xor(s0, 32);
  s1 += __shfl_xor(s1, 16);
  s1 += __shfl_xor(s1, 32);
  float rs[2] = {s0, s1};

  // ---------------- matmul2: h'·l = P @ Wh ----------------
  f32x4 acc2[2][8];
#pragma unroll
  for (int rt = 0; rt < 2; ++rt)
#pragma unroll
    for (int g = 0; g < 8; ++g) acc2[rt][g] = (f32x4){0.f, 0.f, 0.f, 0.f};

#pragma unroll
  for (int g = 0; g < 8; ++g)
#pragma unroll
    for (int kc = 0; kc < 4; ++kc) {
      const bf16x8 bw = *(const bf16x8*)(&sm.a.Whs[g][kc][lane][0]);
      acc2[0][g] = __builtin_amdgcn_mfma_f32_16x16x32_bf16(af[0][kc], bw, acc2[0][g], 0, 0, 0);
      acc2[1][g] = __builtin_amdgcn_mfma_f32_16x16x32_bf16(af[1][kc], bw, acc2[1][g], 0, 0, 0);
    }
  __syncthreads();  // C: all Whs/f2s reads done before stage overwrites

  // ---------------- normalize + elu + LDS-staged coalesced store ----------------
  float* oblk = out + (size_t)bs * 16384;
#pragma unroll
  for (int rt = 0; rt < 2; ++rt) {
    float inv[4];
#pragma unroll
    for (int r = 0; r < 4; ++r) {
      const float lsum = __shfl(rs[rt], (lane & 48) | (lg * 4 + r));
      inv[r] = __builtin_amdgcn_rcpf(lsum);
    }
#pragma unroll
    for (int r = 0; r < 4; ++r)
#pragma unroll
      for (int g = 0; g < 8; ++g) {
        float v = acc2[rt][g][r] * inv[r];
        v = v > 0.f ? v : __expf(v) - 1.0f;
        sm.stage[w][lg * 4 + r][g * 16 + lr] = v;  // 2-way bank aliasing = free
      }
    // wave-local RAW on stage: compiler inserts lgkmcnt
#pragma unroll
    for (int sstep = 0; sstep < 8; ++sstep) {
      const int row16 = ((sstep & 1) << 3) + (lane >> 3);
      const int cd    = ((sstep >> 1) << 5) + ((lane & 7) << 2);
      f32x4 vv = *(const f32x4*)(&sm.stage[w][row16][cd]);
      *(f32x4*)(oblk + (size_t)(R0 + rt * 16 + row16) * 128 + cd) = vv;
    }
  }
}

}  // namespace

extern "C" void kernel_launch(void* const* d_in, const int* in_sizes, int n_in,
                              void* d_out, int out_size, void* d_ws, size_t ws_size,
                              hipStream_t stream) {
  const float* h   = (const float*)d_in[0];
  const float* Ww  = (const float*)d_in[1];
  const float* Wb  = (const float*)d_in[2];
  const float* a1v = (const float*)d_in[3];
  const float* a2v = (const float*)d_in[4];
  const float* ab  = (const float*)d_in[5];
  const int*   adj = (const int*)d_in[6];
  float* out = (float*)d_out;

  unsigned short* wf   = (unsigned short*)d_ws;
  unsigned int*   adjp = (unsigned int*)((char*)d_ws + 36864);
  float*          ba   = (float*)((char*)d_ws + 38912);

  hipLaunchKernelGGL(prep, dim3(72), dim3(256), 0, stream, Ww, Wb, a1v, a2v, adj, wf, adjp, ba);

  const int BS = in_sizes[0] / 16384;  // 1024
  hipLaunchKernelGGL(gat_mfma, dim3(BS), dim3(256), 0, stream,
                     h, Wb, ab, wf, adjp, ba, out);
}

// Round 15
// 42.848 us; speedup vs baseline: 1.4889x; 1.0003x over previous
//
#include <hip/hip_runtime.h>
#include <hip/hip_bf16.h>
#include <cmath>

namespace {

typedef __attribute__((ext_vector_type(8))) short bf16x8;
typedef __attribute__((ext_vector_type(4))) float f32x4;

constexpr float kNegInf = -1000000000.0f;
constexpr float kSlope  = 0.2f;
constexpr float kLog2e  = 1.44269504088896340736f;

__device__ __forceinline__ unsigned short f2bf(float x) {
  unsigned int u = __float_as_uint(x);
  u = (u + 0x7FFFu + ((u >> 16) & 1u)) >> 16;  // RNE
  return (unsigned short)u;
}
// packed pair via v_cvt_pk_bf16_f32
__device__ __forceinline__ unsigned int f2bf2(float a, float b) {
  __hip_bfloat162 t = __float22bfloat162_rn(float2{a, b});
  union { __hip_bfloat162 h; unsigned int u; } c;
  c.h = t;
  return c.u;
}
__device__ __forceinline__ float exp2_hw(float x) {
#if __has_builtin(__builtin_amdgcn_exp2f)
  return __builtin_amdgcn_exp2f(x);
#else
  float r;
  asm("v_exp_f32 %0, %1\n\ts_nop 1" : "=v"(r) : "v"(x));
  return r;
#endif
}

// ---------------- ws layout ----------------
// [0)      ushort wf[18432]   [W | wa1 wa2] B-frag order, bf16 (wa log2e-scaled)
// [36864)  uint   adjp[512]
// [38912)  float  ba[2]       {log2e*Wb.a1, log2e*Wb.a2}

__global__ void prep(const float* __restrict__ Ww, const float* __restrict__ Wb,
                     const float* __restrict__ a1v, const float* __restrict__ a2v,
                     const int* __restrict__ adj,
                     unsigned short* __restrict__ wf, unsigned int* __restrict__ adjp,
                     float* __restrict__ ba) {
  const int tid = blockIdx.x * 256 + threadIdx.x;  // grid 72*256 = 18432 exactly
  // frag order: wf[g][kc][lane][j] = B[k = kc*32 + (lane>>4)*8 + j][col = g*16 + (lane&15)]
  {
    const int j = tid & 7, l = (tid >> 3) & 63, kc = (tid >> 9) & 3, g = tid >> 11;
    const int k = kc * 32 + ((l >> 4) << 3) + j;
    const int c = l & 15;
    float x = 0.f;
    if (g < 8) {
      x = Ww[k * 128 + g * 16 + c];
    } else if (c < 2) {
      const float* av = (c == 0) ? a1v : a2v;
      float s = 0.f;
      for (int q = 0; q < 32; ++q) {
        f32x4 wv = *(const f32x4*)(Ww + k * 128 + q * 4);
        f32x4 aa = *(const f32x4*)(av + q * 4);
        s = fmaf(wv[0], aa[0], fmaf(wv[1], aa[1], fmaf(wv[2], aa[2], fmaf(wv[3], aa[3], s))));
      }
      x = s * kLog2e;  // wa1/wa2, pre-scaled for exp2 domain
    }
    wf[tid] = f2bf(x);
  }
  if (tid < 512) {
    const int row = tid >> 2, wd = tid & 3;
    const int* ap = adj + row * 128 + wd * 32;
    unsigned int bits = 0u;
#pragma unroll
    for (int b = 0; b < 32; ++b) bits |= (ap[b] != 0 ? (1u << b) : 0u);
    adjp[tid] = bits;
  }
  if (tid >= 18368) {  // last wave: ba via butterfly
    const int l = tid - 18368;
    float p1 = Wb[l] * a1v[l] + Wb[l + 64] * a1v[l + 64];
    float p2 = Wb[l] * a2v[l] + Wb[l + 64] * a2v[l + 64];
#pragma unroll
    for (int m = 1; m < 64; m <<= 1) {
      p1 += __shfl_xor(p1, m);
      p2 += __shfl_xor(p2, m);
    }
    if (l == 0) {
      ba[0] = p1 * kLog2e;
      ba[1] = p2 * kLog2e;
    }
  }
}

// LDS: 36864 B (one union, three phased lifetimes) -> 4 blocks/CU = 16 waves/CU
union SMemU {
  unsigned short wfs[9][4][64][8];    // 36864: [W|wa] B-frags, live through mm1 only
  struct {
    unsigned short Whs[8][4][64][8];  // 32768: Wh in B-frag order (post-mm1 .. mm2)
    float f1s[128];                   // log2 domain
    float f2s[128];
  } a;
  float stage[4][16][132];            // 33792: epilogue store stage
};

__global__ __launch_bounds__(256, 4) void gat_mfma(
    const float* __restrict__ h,     // [BS][128][128]
    const float* __restrict__ Wb,    // [128]
    const float* __restrict__ abp,   // [1]
    const unsigned short* __restrict__ wf,
    const unsigned int* __restrict__ adjp,
    const float* __restrict__ ba,
    float* __restrict__ out) {       // [BS][128][128]
  __shared__ SMemU sm;
  const int t    = threadIdx.x;
  const int lane = t & 63;
  const int w    = t >> 6;       // wave 0..3
  const int lr   = lane & 15;
  const int lg   = lane >> 4;    // 0..3
  const int bs   = blockIdx.x;
  const int R0   = w * 32;
  const float ab2 = abp[0] * kLog2e;
  const float ba1 = ba[0], ba2v = ba[1];

  // adjacency rows for this thread's two P-rows: loop-invariant, L2-broadcast
  unsigned int aw0q[4], aw1q[4];
  {
    const int rq0 = (R0 + lr) * 4, rq1 = (R0 + 16 + lr) * 4;
#pragma unroll
    for (int kc = 0; kc < 4; ++kc) {
      aw0q[kc] = adjp[rq0 + kc];
      aw1q[kc] = adjp[rq1 + kc];
    }
  }

  // ---- head: coalesced wf loads (L2) + h loads; stage wf -> LDS ----
  f32x4 wtmp[9];
  {
    const f32x4* wfg = (const f32x4*)wf;  // 2304 f32x4 total
#pragma unroll
    for (int p = 0; p < 9; ++p) wtmp[p] = wfg[p * 256 + t];
  }

  const float* hblk = h + (size_t)bs * 16384;
  bf16x8 ha[2][4];
#pragma unroll
  for (int rt = 0; rt < 2; ++rt)
#pragma unroll
    for (int kc = 0; kc < 4; ++kc) {
      const float* p = hblk + (R0 + rt * 16 + lr) * 128 + kc * 32 + lg * 8;
      f32x4 v0 = *(const f32x4*)p;
      f32x4 v1 = *(const f32x4*)(p + 4);
      union { bf16x8 v; unsigned int u[4]; } pk;
      pk.u[0] = f2bf2(v0[0], v0[1]);
      pk.u[1] = f2bf2(v0[2], v0[3]);
      pk.u[2] = f2bf2(v1[0], v1[1]);
      pk.u[3] = f2bf2(v1[2], v1[3]);
      ha[rt][kc] = pk.v;
    }

  {  // stage wf into LDS (linear copy; frag order preserved)
    f32x4* wfl = (f32x4*)sm.wfs;
#pragma unroll
    for (int p = 0; p < 9; ++p) wfl[p * 256 + t] = wtmp[p];
  }
  __syncthreads();  // 0: wfs visible

  // ---------------- matmul1: [Wh | f1 f2] = bf16(h) @ wfs  (B-frags from LDS) ----------------
  f32x4 acc[2][9];
#pragma unroll
  for (int rt = 0; rt < 2; ++rt)
#pragma unroll
    for (int g = 0; g < 9; ++g) acc[rt][g] = (f32x4){0.f, 0.f, 0.f, 0.f};

#pragma unroll
  for (int g = 0; g < 9; ++g)
#pragma unroll
    for (int kc = 0; kc < 4; ++kc) {
      const bf16x8 bh = *(const bf16x8*)(&sm.wfs[g][kc][lane][0]);
      acc[0][g] = __builtin_amdgcn_mfma_f32_16x16x32_bf16(ha[0][kc], bh, acc[0][g], 0, 0, 0);
      acc[1][g] = __builtin_amdgcn_mfma_f32_16x16x32_bf16(ha[1][kc], bh, acc[1][g], 0, 0, 0);
    }
  __syncthreads();  // A: all waves done reading wfs before Whs overwrites it

  // ---- bias + f1/f2 scatter + Wh -> LDS (B-frag order, bf16) ----
  float wbc[8];
#pragma unroll
  for (int g = 0; g < 8; ++g) wbc[g] = Wb[g * 16 + lr];

#pragma unroll
  for (int rt = 0; rt < 2; ++rt) {
#pragma unroll
    for (int r = 0; r < 4; ++r) {
      // C/D layout: row = R0 + rt*16 + lg*4 + r, col = g*16 + lr
#pragma unroll
      for (int g = 0; g < 8; ++g) acc[rt][g][r] += wbc[g];
      const int row = R0 + rt * 16 + lg * 4 + r;
      if (lr == 0)      sm.a.f1s[row] = acc[rt][8][r] + ba1;
      else if (lr == 1) sm.a.f2s[row] = acc[rt][8][r] + ba2v;
    }
#pragma unroll
    for (int g = 0; g < 8; ++g) {
      const unsigned int plo = f2bf2(acc[rt][g][0], acc[rt][g][1]);
      const unsigned int phi = f2bf2(acc[rt][g][2], acc[rt][g][3]);
      const int lp = (2 * rt + (lg >> 1)) * 16 + lr;
      const int jb = (lg & 1) * 4;
      *(uint2*)(&sm.a.Whs[g][w][lp][jb]) = make_uint2(plo, phi);
    }
  }
  __syncthreads();  // B: Whs/f1/f2 visible

  // ---------------- P-build: single pass, no max-sub (log2 domain, exp2) ----------------
  bf16x8 af[2][4];
  float s0 = 0.f, s1 = 0.f;
  const float f1i0 = sm.a.f1s[R0 + lr] + ab2;
  const float f1i1 = sm.a.f1s[R0 + 16 + lr] + ab2;
#pragma unroll
  for (int kc = 0; kc < 4; ++kc) {
    const f32x4 fv0 = *(const f32x4*)(&sm.a.f2s[kc * 32 + lg * 8]);
    const f32x4 fv1 = *(const f32x4*)(&sm.a.f2s[kc * 32 + lg * 8 + 4]);
    const unsigned int aw0 = aw0q[kc];
    const unsigned int aw1 = aw1q[kc];
    union { bf16x8 v; unsigned int u[4]; } pk0, pk1;
#pragma unroll
    for (int qq = 0; qq < 4; ++qq) {
      float e0[2], e1[2];
#pragma unroll
      for (int hh = 0; hh < 2; ++hh) {
        const int q = qq * 2 + hh;
        const float fj = (q < 4) ? fv0[q] : fv1[q - 4];
        const unsigned int bit = 1u << (lg * 8 + q);
        float x0 = f1i0 + fj;
        x0 = x0 >= 0.f ? x0 : kSlope * x0;
        x0 = (aw0 & bit) ? x0 : kNegInf;
        e0[hh] = exp2_hw(x0);
        float x1 = f1i1 + fj;
        x1 = x1 >= 0.f ? x1 : kSlope * x1;
        x1 = (aw1 & bit) ? x1 : kNegInf;
        e1[hh] = exp2_hw(x1);
      }
      const unsigned int u0 = f2bf2(e0[0], e0[1]);
      const unsigned int u1 = f2bf2(e1[0], e1[1]);
      pk0.u[qq] = u0;
      pk1.u[qq] = u1;
      s0 += __uint_as_float(u0 << 16) + __uint_as_float(u0 & 0xffff0000u);
      s1 += __uint_as_float(u1 << 16) + __uint_as_float(u1 & 0xffff0000u);
    }
    af[0][kc] = pk0.v;
    af[1][kc] = pk1.v;
  }
  s0 += __shfl_xor(s0, 16);
  s0 += __shfl_xor(s0, 32);
  s1 += __shfl_xor(s1, 16);
  s1 += __shfl_xor(s1, 32);
  float rs[2] = {s0, s1};

  // ---------------- matmul2: h'·l = P @ Wh ----------------
  f32x4 acc2[2][8];
#pragma unroll
  for (int rt = 0; rt < 2; ++rt)
#pragma unroll
    for (int g = 0; g < 8; ++g) acc2[rt][g] = (f32x4){0.f, 0.f, 0.f, 0.f};

#pragma unroll
  for (int g = 0; g < 8; ++g)
#pragma unroll
    for (int kc = 0; kc < 4; ++kc) {
      const bf16x8 bw = *(const bf16x8*)(&sm.a.Whs[g][kc][lane][0]);
      acc2[0][g] = __builtin_amdgcn_mfma_f32_16x16x32_bf16(af[0][kc], bw, acc2[0][g], 0, 0, 0);
      acc2[1][g] = __builtin_amdgcn_mfma_f32_16x16x32_bf16(af[1][kc], bw, acc2[1][g], 0, 0, 0);
    }
  __syncthreads();  // C: all Whs/f2s reads done before stage overwrites

  // ---------------- normalize + elu + LDS-staged coalesced store ----------------
  float* oblk = out + (size_t)bs * 16384;
#pragma unroll
  for (int rt = 0; rt < 2; ++rt) {
    float inv[4];
#pragma unroll
    for (int r = 0; r < 4; ++r) {
      const float lsum = __shfl(rs[rt], (lane & 48) | (lg * 4 + r));
      inv[r] = __builtin_amdgcn_rcpf(lsum);
    }
#pragma unroll
    for (int r = 0; r < 4; ++r)
#pragma unroll
      for (int g = 0; g < 8; ++g) {
        float v = acc2[rt][g][r] * inv[r];
        v = v > 0.f ? v : __expf(v) - 1.0f;
        sm.stage[w][lg * 4 + r][g * 16 + lr] = v;  // 2-way bank aliasing = free
      }
    // wave-local RAW on stage: compiler inserts lgkmcnt
#pragma unroll
    for (int sstep = 0; sstep < 8; ++sstep) {
      const int row16 = ((sstep & 1) << 3) + (lane >> 3);
      const int cd    = ((sstep >> 1) << 5) + ((lane & 7) << 2);
      f32x4 vv = *(const f32x4*)(&sm.stage[w][row16][cd]);
      *(f32x4*)(oblk + (size_t)(R0 + rt * 16 + row16) * 128 + cd) = vv;
    }
  }
}

}  // namespace

extern "C" void kernel_launch(void* const* d_in, const int* in_sizes, int n_in,
                              void* d_out, int out_size, void* d_ws, size_t ws_size,
                              hipStream_t stream) {
  const float* h   = (const float*)d_in[0];
  const float* Ww  = (const float*)d_in[1];
  const float* Wb  = (const float*)d_in[2];
  const float* a1v = (const float*)d_in[3];
  const float* a2v = (const float*)d_in[4];
  const float* ab  = (const float*)d_in[5];
  const int*   adj = (const int*)d_in[6];
  float* out = (float*)d_out;

  unsigned short* wf   = (unsigned short*)d_ws;
  unsigned int*   adjp = (unsigned int*)((char*)d_ws + 36864);
  float*          ba   = (float*)((char*)d_ws + 38912);

  hipLaunchKernelGGL(prep, dim3(72), dim3(256), 0, stream, Ww, Wb, a1v, a2v, adj, wf, adjp, ba);

  const int BS = in_sizes[0] / 16384;  // 1024
  hipLaunchKernelGGL(gat_mfma, dim3(BS), dim3(256), 0, stream,
                     h, Wb, ab, wf, adjp, ba, out);
}

// Round 16
// 40.657 us; speedup vs baseline: 1.5692x; 1.0539x over previous
//
#include <hip/hip_runtime.h>
#include <hip/hip_bf16.h>
#include <cmath>

namespace {

typedef __attribute__((ext_vector_type(8))) short bf16x8;
typedef __attribute__((ext_vector_type(4))) float f32x4;

constexpr float kNegInf = -1000000000.0f;
constexpr float kSlope  = 0.2f;
constexpr float kLog2e  = 1.44269504088896340736f;

__device__ __forceinline__ unsigned short f2bf(float x) {
  unsigned int u = __float_as_uint(x);
  u = (u + 0x7FFFu + ((u >> 16) & 1u)) >> 16;  // RNE
  return (unsigned short)u;
}
// packed pair via v_cvt_pk_bf16_f32
__device__ __forceinline__ unsigned int f2bf2(float a, float b) {
  __hip_bfloat162 t = __float22bfloat162_rn(float2{a, b});
  union { __hip_bfloat162 h; unsigned int u; } c;
  c.h = t;
  return c.u;
}
__device__ __forceinline__ float exp2_hw(float x) {
#if __has_builtin(__builtin_amdgcn_exp2f)
  return __builtin_amdgcn_exp2f(x);
#else
  float r;
  asm("v_exp_f32 %0, %1\n\ts_nop 1" : "=v"(r) : "v"(x));
  return r;
#endif
}

// ---------------- ws layout ----------------
// [0)      ushort wf[18432]   [W | wa1 wa2] B-frag order, bf16 (wa log2e-scaled)
// [36864)  uint   adjp[512]
// [38912)  float  ba[2]       {log2e*Wb.a1, log2e*Wb.a2}

__global__ void prep(const float* __restrict__ Ww, const float* __restrict__ Wb,
                     const float* __restrict__ a1v, const float* __restrict__ a2v,
                     const int* __restrict__ adj,
                     unsigned short* __restrict__ wf, unsigned int* __restrict__ adjp,
                     float* __restrict__ ba) {
  const int tid = blockIdx.x * 256 + threadIdx.x;  // grid 72*256 = 18432 exactly
  // frag order: wf[g][kc][lane][j] = B[k = kc*32 + (lane>>4)*8 + j][col = g*16 + (lane&15)]
  {
    const int j = tid & 7, l = (tid >> 3) & 63, kc = (tid >> 9) & 3, g = tid >> 11;
    const int k = kc * 32 + ((l >> 4) << 3) + j;
    const int c = l & 15;
    float x = 0.f;
    if (g < 8) {
      x = Ww[k * 128 + g * 16 + c];
    } else if (c < 2) {
      const float* av = (c == 0) ? a1v : a2v;
      float s = 0.f;
      for (int q = 0; q < 32; ++q) {
        f32x4 wv = *(const f32x4*)(Ww + k * 128 + q * 4);
        f32x4 aa = *(const f32x4*)(av + q * 4);
        s = fmaf(wv[0], aa[0], fmaf(wv[1], aa[1], fmaf(wv[2], aa[2], fmaf(wv[3], aa[3], s))));
      }
      x = s * kLog2e;  // wa1/wa2, pre-scaled for exp2 domain
    }
    wf[tid] = f2bf(x);
  }
  if (tid < 512) {
    const int row = tid >> 2, wd = tid & 3;
    const int* ap = adj + row * 128 + wd * 32;
    unsigned int bits = 0u;
#pragma unroll
    for (int b = 0; b < 32; ++b) bits |= (ap[b] != 0 ? (1u << b) : 0u);
    adjp[tid] = bits;
  }
  if (tid >= 18368) {  // last wave: ba via butterfly
    const int l = tid - 18368;
    float p1 = Wb[l] * a1v[l] + Wb[l + 64] * a1v[l + 64];
    float p2 = Wb[l] * a2v[l] + Wb[l + 64] * a2v[l + 64];
#pragma unroll
    for (int m = 1; m < 64; m <<= 1) {
      p1 += __shfl_xor(p1, m);
      p2 += __shfl_xor(p2, m);
    }
    if (l == 0) {
      ba[0] = p1 * kLog2e;
      ba[1] = p2 * kLog2e;
    }
  }
}

// LDS: 36864 B (one union, three phased lifetimes) -> 4 blocks/CU = 16 waves/CU
union SMemU {
  unsigned short wfs[9][4][64][8];    // 36864: [W|wa] B-frags, live through mm1 only
  struct {
    unsigned short Whs[8][4][64][8];  // 32768: Wh in B-frag order (post-mm1 .. mm2)
    float f1s[128];                   // log2 domain
    float f2s[128];
  } a;
  float stage[4][16][132];            // 33792: epilogue store stage
};

__global__ __launch_bounds__(256, 4) void gat_mfma(
    const float* __restrict__ h,     // [BS][128][128]
    const float* __restrict__ Wb,    // [128]
    const float* __restrict__ abp,   // [1]
    const unsigned short* __restrict__ wf,
    const unsigned int* __restrict__ adjp,
    const float* __restrict__ ba,
    float* __restrict__ out) {       // [BS][128][128]
  __shared__ SMemU sm;
  const int t    = threadIdx.x;
  const int lane = t & 63;
  const int w    = t >> 6;       // wave 0..3
  const int lr   = lane & 15;
  const int lg   = lane >> 4;    // 0..3
  const int bs   = blockIdx.x;
  const int R0   = w * 32;
  const float ab2 = abp[0] * kLog2e;
  const float ba1 = ba[0], ba2v = ba[1];

  // adjacency rows for this thread's two P-rows: loop-invariant, L2-broadcast
  unsigned int aw0q[4], aw1q[4];
  {
    const int rq0 = (R0 + lr) * 4, rq1 = (R0 + 16 + lr) * 4;
#pragma unroll
    for (int kc = 0; kc < 4; ++kc) {
      aw0q[kc] = adjp[rq0 + kc];
      aw1q[kc] = adjp[rq1 + kc];
    }
  }

  // ---- head: coalesced wf loads (L2, cached) + h loads (streaming, NT) ----
  f32x4 wtmp[9];
  {
    const f32x4* wfg = (const f32x4*)wf;  // 2304 f32x4 total
#pragma unroll
    for (int p = 0; p < 9; ++p) wtmp[p] = wfg[p * 256 + t];
  }

  const float* hblk = h + (size_t)bs * 16384;
  bf16x8 ha[2][4];
#pragma unroll
  for (int rt = 0; rt < 2; ++rt)
#pragma unroll
    for (int kc = 0; kc < 4; ++kc) {
      const float* p = hblk + (R0 + rt * 16 + lr) * 128 + kc * 32 + lg * 8;
      f32x4 v0 = __builtin_nontemporal_load((const f32x4*)p);       // h read exactly once
      f32x4 v1 = __builtin_nontemporal_load((const f32x4*)(p + 4));
      union { bf16x8 v; unsigned int u[4]; } pk;
      pk.u[0] = f2bf2(v0[0], v0[1]);
      pk.u[1] = f2bf2(v0[2], v0[3]);
      pk.u[2] = f2bf2(v1[0], v1[1]);
      pk.u[3] = f2bf2(v1[2], v1[3]);
      ha[rt][kc] = pk.v;
    }

  {  // stage wf into LDS (linear copy; frag order preserved)
    f32x4* wfl = (f32x4*)sm.wfs;
#pragma unroll
    for (int p = 0; p < 9; ++p) wfl[p * 256 + t] = wtmp[p];
  }
  __syncthreads();  // 0: wfs visible

  // ---------------- matmul1: [Wh | f1 f2] = bf16(h) @ wfs  (B-frags from LDS) ----------------
  f32x4 acc[2][9];
#pragma unroll
  for (int rt = 0; rt < 2; ++rt)
#pragma unroll
    for (int g = 0; g < 9; ++g) acc[rt][g] = (f32x4){0.f, 0.f, 0.f, 0.f};

#pragma unroll
  for (int g = 0; g < 9; ++g)
#pragma unroll
    for (int kc = 0; kc < 4; ++kc) {
      const bf16x8 bh = *(const bf16x8*)(&sm.wfs[g][kc][lane][0]);
      acc[0][g] = __builtin_amdgcn_mfma_f32_16x16x32_bf16(ha[0][kc], bh, acc[0][g], 0, 0, 0);
      acc[1][g] = __builtin_amdgcn_mfma_f32_16x16x32_bf16(ha[1][kc], bh, acc[1][g], 0, 0, 0);
    }
  __syncthreads();  // A: all waves done reading wfs before Whs overwrites it

  // ---- bias + f1/f2 scatter + Wh -> LDS (B-frag order, bf16) ----
  float wbc[8];
#pragma unroll
  for (int g = 0; g < 8; ++g) wbc[g] = Wb[g * 16 + lr];

#pragma unroll
  for (int rt = 0; rt < 2; ++rt) {
#pragma unroll
    for (int r = 0; r < 4; ++r) {
      // C/D layout: row = R0 + rt*16 + lg*4 + r, col = g*16 + lr
#pragma unroll
      for (int g = 0; g < 8; ++g) acc[rt][g][r] += wbc[g];
      const int row = R0 + rt * 16 + lg * 4 + r;
      if (lr == 0)      sm.a.f1s[row] = acc[rt][8][r] + ba1;
      else if (lr == 1) sm.a.f2s[row] = acc[rt][8][r] + ba2v;
    }
#pragma unroll
    for (int g = 0; g < 8; ++g) {
      const unsigned int plo = f2bf2(acc[rt][g][0], acc[rt][g][1]);
      const unsigned int phi = f2bf2(acc[rt][g][2], acc[rt][g][3]);
      const int lp = (2 * rt + (lg >> 1)) * 16 + lr;
      const int jb = (lg & 1) * 4;
      *(uint2*)(&sm.a.Whs[g][w][lp][jb]) = make_uint2(plo, phi);
    }
  }
  __syncthreads();  // B: Whs/f1/f2 visible

  // ---------------- P-build: single pass, no max-sub (log2 domain, exp2) ----------------
  bf16x8 af[2][4];
  float s0 = 0.f, s1 = 0.f;
  const float f1i0 = sm.a.f1s[R0 + lr] + ab2;
  const float f1i1 = sm.a.f1s[R0 + 16 + lr] + ab2;
#pragma unroll
  for (int kc = 0; kc < 4; ++kc) {
    const f32x4 fv0 = *(const f32x4*)(&sm.a.f2s[kc * 32 + lg * 8]);
    const f32x4 fv1 = *(const f32x4*)(&sm.a.f2s[kc * 32 + lg * 8 + 4]);
    const unsigned int aw0 = aw0q[kc];
    const unsigned int aw1 = aw1q[kc];
    union { bf16x8 v; unsigned int u[4]; } pk0, pk1;
#pragma unroll
    for (int qq = 0; qq < 4; ++qq) {
      float e0[2], e1[2];
#pragma unroll
      for (int hh = 0; hh < 2; ++hh) {
        const int q = qq * 2 + hh;
        const float fj = (q < 4) ? fv0[q] : fv1[q - 4];
        const unsigned int bit = 1u << (lg * 8 + q);
        float x0 = f1i0 + fj;
        x0 = fmaxf(x0, kSlope * x0);          // leaky: bit-exact, mul+max
        x0 = (aw0 & bit) ? x0 : kNegInf;
        e0[hh] = exp2_hw(x0);
        float x1 = f1i1 + fj;
        x1 = fmaxf(x1, kSlope * x1);
        x1 = (aw1 & bit) ? x1 : kNegInf;
        e1[hh] = exp2_hw(x1);
      }
      const unsigned int u0 = f2bf2(e0[0], e0[1]);
      const unsigned int u1 = f2bf2(e1[0], e1[1]);
      pk0.u[qq] = u0;
      pk1.u[qq] = u1;
      s0 += __uint_as_float(u0 << 16) + __uint_as_float(u0 & 0xffff0000u);
      s1 += __uint_as_float(u1 << 16) + __uint_as_float(u1 & 0xffff0000u);
    }
    af[0][kc] = pk0.v;
    af[1][kc] = pk1.v;
  }
  s0 += __shfl_xor(s0, 16);
  s0 += __shfl_xor(s0, 32);
  s1 += __shfl_xor(s1, 16);
  s1 += __shfl_xor(s1, 32);
  float rs[2] = {s0, s1};

  // ---------------- matmul2: h'·l = P @ Wh ----------------
  f32x4 acc2[2][8];
#pragma unroll
  for (int rt = 0; rt < 2; ++rt)
#pragma unroll
    for (int g = 0; g < 8; ++g) acc2[rt][g] = (f32x4){0.f, 0.f, 0.f, 0.f};

#pragma unroll
  for (int g = 0; g < 8; ++g)
#pragma unroll
    for (int kc = 0; kc < 4; ++kc) {
      const bf16x8 bw = *(const bf16x8*)(&sm.a.Whs[g][kc][lane][0]);
      acc2[0][g] = __builtin_amdgcn_mfma_f32_16x16x32_bf16(af[0][kc], bw, acc2[0][g], 0, 0, 0);
      acc2[1][g] = __builtin_amdgcn_mfma_f32_16x16x32_bf16(af[1][kc], bw, acc2[1][g], 0, 0, 0);
    }
  __syncthreads();  // C: all Whs/f2s reads done before stage overwrites

  // ---------------- normalize + elu + LDS-staged coalesced NT store ----------------
  float* oblk = out + (size_t)bs * 16384;
#pragma unroll
  for (int rt = 0; rt < 2; ++rt) {
    float inv[4];
#pragma unroll
    for (int r = 0; r < 4; ++r) {
      const float lsum = __shfl(rs[rt], (lane & 48) | (lg * 4 + r));
      inv[r] = __builtin_amdgcn_rcpf(lsum);
    }
#pragma unroll
    for (int r = 0; r < 4; ++r)
#pragma unroll
      for (int g = 0; g < 8; ++g) {
        float v = acc2[rt][g][r] * inv[r];
        v = v > 0.f ? v : __expf(v) - 1.0f;
        sm.stage[w][lg * 4 + r][g * 16 + lr] = v;  // 2-way bank aliasing = free
      }
    // wave-local RAW on stage: compiler inserts lgkmcnt
#pragma unroll
    for (int sstep = 0; sstep < 8; ++sstep) {
      const int row16 = ((sstep & 1) << 3) + (lane >> 3);
      const int cd    = ((sstep >> 1) << 5) + ((lane & 7) << 2);
      f32x4 vv = *(const f32x4*)(&sm.stage[w][row16][cd]);
      __builtin_nontemporal_store(vv, (f32x4*)(oblk + (size_t)(R0 + rt * 16 + row16) * 128 + cd));
    }
  }
}

}  // namespace

extern "C" void kernel_launch(void* const* d_in, const int* in_sizes, int n_in,
                              void* d_out, int out_size, void* d_ws, size_t ws_size,
                              hipStream_t stream) {
  const float* h   = (const float*)d_in[0];
  const float* Ww  = (const float*)d_in[1];
  const float* Wb  = (const float*)d_in[2];
  const float* a1v = (const float*)d_in[3];
  const float* a2v = (const float*)d_in[4];
  const float* ab  = (const float*)d_in[5];
  const int*   adj = (const int*)d_in[6];
  float* out = (float*)d_out;

  unsigned short* wf   = (unsigned short*)d_ws;
  unsigned int*   adjp = (unsigned int*)((char*)d_ws + 36864);
  float*          ba   = (float*)((char*)d_ws + 38912);

  hipLaunchKernelGGL(prep, dim3(72), dim3(256), 0, stream, Ww, Wb, a1v, a2v, adj, wf, adjp, ba);

  const int BS = in_sizes[0] / 16384;  // 1024
  hipLaunchKernelGGL(gat_mfma, dim3(BS), dim3(256), 0, stream,
                     h, Wb, ab, wf, adjp, ba, out);
}